// Round 9
// baseline (315.449 us; speedup 1.0000x reference)
//
#include <hip/hip_runtime.h>
#include <hip/hip_bf16.h>

typedef short v8s __attribute__((ext_vector_type(8)));
typedef float v4f __attribute__((ext_vector_type(4)));
typedef __hip_bfloat16 bf16;
typedef unsigned int u32;

#define MFMA(a, b, c) __builtin_amdgcn_mfma_f32_16x16x32_bf16(a, b, c, 0, 0, 0)

// direct global->LDS DMA, 16B per lane. LDS dest = wave-uniform base + lane*16.
__device__ __forceinline__ void gload16(const bf16* g, bf16* l) {
    __builtin_amdgcn_global_load_lds(
        (const __attribute__((address_space(1))) u32*)(g),
        (__attribute__((address_space(3))) u32*)(l), 16, 0, 0);
}

// ---------------------------------------------------------------------------
// All fp32->bf16 casts in ONE launch. grid=(4096,6); region r sized n4 vec4s.
// ---------------------------------------------------------------------------
__global__ __launch_bounds__(256) void cast_all(
    const float* __restrict__ x,  const float* __restrict__ wq,
    const float* __restrict__ wk, const float* __restrict__ wv,
    const float* __restrict__ wo, const float* __restrict__ er,
    bf16* __restrict__ xb,  bf16* __restrict__ wqb, bf16* __restrict__ wkb,
    bf16* __restrict__ wvb, bf16* __restrict__ wob, bf16* __restrict__ erb)
{
    const int r = blockIdx.y;
    const float* s; bf16* d; int n4;
    if      (r == 0) { s = x;  d = xb;  n4 = 1048576; }
    else if (r == 1) { s = wq; d = wqb; n4 = 262144;  }
    else if (r == 2) { s = wk; d = wkb; n4 = 262144;  }
    else if (r == 3) { s = wv; d = wvb; n4 = 262144;  }
    else if (r == 4) { s = wo; d = wob; n4 = 262144;  }
    else             { s = er; d = erb; n4 = 32768;   }
    const int i = blockIdx.x * 256 + threadIdx.x;
    if (i < n4) {
        const float4 v = ((const float4*)s)[i];
        bf16 t[4];
        t[0] = __float2bfloat16(v.x);
        t[1] = __float2bfloat16(v.y);
        t[2] = __float2bfloat16(v.z);
        t[3] = __float2bfloat16(v.w);
        ((uint2*)d)[i] = *(const uint2*)t;
    }
}

// ---------------------------------------------------------------------------
// NT GEMM v4 (unchanged; R6 probe measured qkv+proj at ~65 us total ~530 TF).
// ---------------------------------------------------------------------------
__global__ __launch_bounds__(256) void gemm_nt(
    const bf16* __restrict__ A, const bf16* __restrict__ W,
    const float* __restrict__ b0, const float* __restrict__ b1,
    const float* __restrict__ b2,
    bf16* __restrict__ oHM, bf16* __restrict__ Vt, float* __restrict__ outf)
{
    __shared__ bf16 As[2][128 * 64];
    __shared__ bf16 Bs[2][128 * 64];

    const int tid = threadIdx.x;
    const int w  = tid >> 6, l = tid & 63;
    const int lm = l & 15,  lq = l >> 4;
    const int wm = (w >> 1) * 64, wn = (w & 1) * 64;
    const int m0 = blockIdx.y * 128, n0 = blockIdx.x * 128;

    const int grow = l >> 3;                       // 0..7, == row&7
    const int gcol = ((l & 7) ^ grow) * 8;         // bf16 units, 16B granules

    v4f acc[4][4];
#pragma unroll
    for (int i = 0; i < 4; ++i)
#pragma unroll
        for (int j = 0; j < 4; ++j) acc[i][j] = (v4f){0.f, 0.f, 0.f, 0.f};

    const int sw = (lm & 7) << 4;

    auto STAGE = [&](int p, int k0) {
#pragma unroll
        for (int q = 0; q < 4; ++q) {
            const int rr = w * 32 + q * 8;
            gload16(&A[(size_t)(m0 + rr + grow) * 1024 + k0 + gcol], &As[p][rr * 64]);
            gload16(&W[(size_t)(n0 + rr + grow) * 1024 + k0 + gcol], &Bs[p][rr * 64]);
        }
    };
    auto COMPUTE = [&](int p) {
#pragma unroll
        for (int kk = 0; kk < 2; ++kk) {
            v8s a[4], b[4];
            const int cb = (lq * 16 + kk * 64);
#pragma unroll
            for (int i = 0; i < 4; ++i) {
                const int row = wm + i * 16 + lm;
                a[i] = *(const v8s*)((const char*)As[p] + row * 128 + (cb ^ sw));
            }
#pragma unroll
            for (int j = 0; j < 4; ++j) {
                const int row = wn + j * 16 + lm;
                b[j] = *(const v8s*)((const char*)Bs[p] + row * 128 + (cb ^ sw));
            }
#pragma unroll
            for (int i = 0; i < 4; ++i)
#pragma unroll
                for (int j = 0; j < 4; ++j)
                    acc[i][j] = MFMA(b[j], a[i], acc[i][j]);   // SWAPPED: C^T frag
        }
    };

    STAGE(0, 0);
    __syncthreads();                               // tile 0 landed
    for (int t = 0; t < 15; ++t) {
        STAGE((t + 1) & 1, (t + 1) * 64);          // issue next tile's DMA
        COMPUTE(t & 1);                            // overlap under it
        __syncthreads();                           // drain vmcnt; all reads done
    }
    COMPUTE(1);                                    // tile 15

    const int z = blockIdx.x >> 3;                 // 1024-col slab
    const float* bias = (z == 0) ? b0 : (z == 1) ? b1 : b2;

    float4 bj[4];
#pragma unroll
    for (int j = 0; j < 4; ++j)
        bj[j] = *(const float4*)&bias[(n0 & 1023) + wn + j * 16 + lq * 4];

#pragma unroll
    for (int i = 0; i < 4; ++i) {
        const int row = m0 + wm + i * 16 + lm;     // one row per lane
        const int bb = row >> 11, ss = row & 2047;
#pragma unroll
        for (int j = 0; j < 4; ++j) {
            const int cc = (n0 & 1023) + wn + j * 16 + lq * 4;
            const float v0 = acc[i][j][0] + bj[j].x;
            const float v1 = acc[i][j][1] + bj[j].y;
            const float v2 = acc[i][j][2] + bj[j].z;
            const float v3 = acc[i][j][3] + bj[j].w;
            if (outf) {
                const float4 fv = {v0, v1, v2, v3};
                *(float4*)&outf[(size_t)row * 1024 + cc] = fv;
            } else {
                bf16 t[4];
                t[0] = __float2bfloat16(v0);
                t[1] = __float2bfloat16(v1);
                t[2] = __float2bfloat16(v2);
                t[3] = __float2bfloat16(v3);
                const int hh = cc >> 6, dd = cc & 63;
                if (z < 2) {
                    *(uint2*)&oHM[(size_t)z * 4194304 +
                        ((size_t)(bb * 16 + hh) * 2048 + ss) * 64 + dd] = *(uint2*)t;
                } else {
#pragma unroll
                    for (int r = 0; r < 4; ++r)
                        Vt[((size_t)(bb * 16 + hh) * 64 + dd + r) * 2048 + ss] = t[r];
                }
            }
        }
    }
}

// ---------------------------------------------------------------------------
// Flash attention + skewed rel-pos bias, v8: QBLK=128, two q-sets per wave.
// R1-R8 evidence: VALUBusy*dur and MfmaUtil*dur are INVARIANT (~32 / ~11.5
// us-equiv) across every schedule variant; no pipe >27% busy; occupancy,
// FETCH, and conflict reductions all null. attn is LATENCY-bound on each
// wave's serial per-iteration chain (Er L2 load -> dep MFMA pairs -> exp ->
// P LDS roundtrip -> dep MFMA), lockstep barriers prevent cross-wave hiding.
// Fix: each wave owns TWO 16-row q fragment sets (rows w*32 and w*32+16):
//  - every phase = 2 independent dep-chains -> latency interleaves in-wave;
//  - K-frag reads, V-frag reads, staging, prefetch, barriers amortize 2x;
//  - per-CU block-iters 66 -> 34 at ~1.6x per-iter cost.
// Ps (64 rows) is TIME-SHARED between sets (same-wave DS ordering: scores-A
// -> read paA -> scores-B overwrite -> read paB; v3-proven pattern).
// Split-K/fixup DELETED: 512 blocks, CU pairs (qb2=a, 15-a) = 34 iters each,
// balanced; same-bh ords adjacent, all lockstep from kv tile 0 (L2 property).
// Numerics identical to v3 per q-row. LDS 62464 B -> 2 blocks/CU.
// ---------------------------------------------------------------------------
__global__ __launch_bounds__(256, 2) void attn(
    const bf16* __restrict__ Q, const bf16* __restrict__ K,
    const bf16* __restrict__ Vt, const bf16* __restrict__ Er,
    bf16* __restrict__ AO)
{
    __shared__ bf16 Ks[64 * 72];
    __shared__ bf16 Vs[64 * 72];
    __shared__ bf16 Ps[64 * 72];     // time-shared: set A then set B each iter
    __shared__ bf16 Gs2[128 * 100];  // row q-local, col shifted c''=col'+lm+1

    const int ord = blockIdx.x;
    const int u = ord & 255, j = ord >> 8;
    const int bh = u >> 3, a = u & 7;
    const int qb2 = j ? (15 - a) : a;              // CU pair sums 34 iters
    const int nk = 2 * qb2 + 2;
    const int i0 = qb2 * 128;

    const int b  = bh >> 4, h = bh & 15;
    const int tid = threadIdx.x;
    const int w  = tid >> 6, l = tid & 63;
    const int lm = l & 15,  lq = l >> 4;

    // two q fragment sets: rows w*32+lm (A) and w*32+16+lm (B)
    const bf16* qpA = Q + ((size_t)bh * 2048 + i0 + w * 32 + lm) * 64 + lq * 8;
    const v8s qA0 = *(const v8s*)qpA;
    const v8s qA1 = *(const v8s*)(qpA + 32);
    const v8s qB0 = *(const v8s*)(qpA + 16 * 64);
    const v8s qB1 = *(const v8s*)(qpA + 16 * 64 + 32);

    v4f accA[4], accB[4];
#pragma unroll
    for (int dt = 0; dt < 4; ++dt) {
        accA[dt] = (v4f){0.f, 0.f, 0.f, 0.f};
        accB[dt] = (v4f){0.f, 0.f, 0.f, 0.f};
    }
    float rsA = 0.f, rsB = 0.f;        // denominators for q-rows w*32+lm / +16+lm

    const int sr0 = tid >> 3;          // 0..31 (+32 on rep1)
    const int sc8 = (tid & 7) * 8;
    const size_t kbase = (size_t)bh * 2048 * 64;
    const size_t vbase = (size_t)bh * 64 * 2048;

    const int growA = (w * 32 + lm) * 100;
    const int growB = (w * 32 + 16 + lm) * 100;
    const int prow  = (w * 16 + lm) * 72;          // shared Ps row (wave-private)
    const int igA   = i0 + w * 32 + lm;
    const int igB   = igA + 16;

    // prefetch tile 0
    uint4 kp0 = *(const uint4*)&K[kbase + (size_t)sr0 * 64 + sc8];
    uint4 kp1 = *(const uint4*)&K[kbase + (size_t)(sr0 + 32) * 64 + sc8];
    uint4 vp0 = *(const uint4*)&Vt[vbase + (size_t)sr0 * 2048 + sc8];
    uint4 vp1 = *(const uint4*)&Vt[vbase + (size_t)(sr0 + 32) * 2048 + sc8];

    for (int it = 0; it < nk; ++it) {
        const int j0 = it * 64;
        __syncthreads();                       // prev iter's LDS reads done
        *(uint4*)&Ks[sr0 * 72 + sc8]        = kp0;
        *(uint4*)&Ks[(sr0 + 32) * 72 + sc8] = kp1;
        *(uint4*)&Vs[sr0 * 72 + sc8]        = vp0;
        *(uint4*)&Vs[(sr0 + 32) * 72 + sc8] = vp1;
        if (it + 1 < nk) {                     // prefetch next tile
            const int jn = j0 + 64;
            kp0 = *(const uint4*)&K[kbase + (size_t)(jn + sr0) * 64 + sc8];
            kp1 = *(const uint4*)&K[kbase + (size_t)(jn + sr0 + 32) * 64 + sc8];
            vp0 = *(const uint4*)&Vt[vbase + (size_t)sr0 * 2048 + jn + sc8];
            vp1 = *(const uint4*)&Vt[vbase + (size_t)(sr0 + 32) * 2048 + jn + sc8];
        }
        // G band, both sets (independent chains), S^T layout (v7-proven):
        // MFMA(e,q): lane holds q-row lm, col' = ct2*16+lq*4+r; store shifted
        // by lm+1 so the score gather is a lane-uniform aligned b64.
#pragma unroll
        for (int s2 = 0; s2 < 2; ++s2) {
            const int basew = 2048 - 16 - i0 + j0 - (w * 32 + s2 * 16);
            const int grow = s2 ? growB : growA;
            const v8s qs0 = s2 ? qB0 : qA0;
            const v8s qs1 = s2 ? qB1 : qA1;
#pragma unroll
            for (int ct2 = 0; ct2 < 5; ++ct2) {
                int mr = basew + ct2 * 16 + lm;
                mr = (mr > 2047) ? 2047 : mr;  // clamped rows feed masked cols only
                const bf16* ep = Er + (size_t)mr * 64 + lq * 8;
                const v8s e0 = *(const v8s*)ep;
                const v8s e1 = *(const v8s*)(ep + 32);
                v4f g = (v4f){0.f, 0.f, 0.f, 0.f};
                g = MFMA(e0, qs0, g);
                g = MFMA(e1, qs1, g);
                const int cb = ct2 * 16 + lq * 4 + lm + 1;
#pragma unroll
                for (int r = 0; r < 4; ++r)
                    Gs2[grow + cb + r] = __float2bfloat16(g[r] * 0.125f);
            }
        }
        __syncthreads();                       // K/V staged, visible
        // QK^T both sets; k-frags read once, feed 4 MFMAs each
        v4f svA[4], svB[4];
#pragma unroll
        for (int ct = 0; ct < 4; ++ct) {
            const v8s k0f = *(const v8s*)&Ks[(ct * 16 + lm) * 72 + lq * 8];
            const v8s k1f = *(const v8s*)&Ks[(ct * 16 + lm) * 72 + 32 + lq * 8];
            v4f sa = (v4f){0.f, 0.f, 0.f, 0.f};
            sa = MFMA(k0f, qA0, sa);
            sa = MFMA(k1f, qA1, sa);
            svA[ct] = sa;
            v4f sb = (v4f){0.f, 0.f, 0.f, 0.f};
            sb = MFMA(k0f, qB0, sb);
            sb = MFMA(k1f, qB1, sb);
            svB[ct] = sb;
        }
        // scores set A -> Ps; read paA (same-wave DS order)
#pragma unroll
        for (int ct = 0; ct < 4; ++ct) {
            const uint2 graw = *(const uint2*)&Gs2[growA + 16 + ct * 16 + lq * 4];
            const bf16* gb4 = (const bf16*)&graw;
            bf16 pt[4];
#pragma unroll
            for (int r = 0; r < 4; ++r) {
                const int jj = ct * 16 + lq * 4 + r;
                float sc = fmaf(svA[ct][r], 0.125f, (float)gb4[r]);
                if (j0 + jj > igA) sc = -1e9f;
                const float pe = __expf(sc - 4.0f);
                rsA += pe;
                pt[r] = __float2bfloat16(pe);
            }
            *(uint2*)&Ps[prow + ct * 16 + lq * 4] = *(const uint2*)pt;
        }
        const v8s paA0 = *(const v8s*)&Ps[prow + lq * 8];
        const v8s paA1 = *(const v8s*)&Ps[prow + 32 + lq * 8];
        // scores set B -> Ps (overwrites; paA already read); read paB
#pragma unroll
        for (int ct = 0; ct < 4; ++ct) {
            const uint2 graw = *(const uint2*)&Gs2[growB + 16 + ct * 16 + lq * 4];
            const bf16* gb4 = (const bf16*)&graw;
            bf16 pt[4];
#pragma unroll
            for (int r = 0; r < 4; ++r) {
                const int jj = ct * 16 + lq * 4 + r;
                float sc = fmaf(svB[ct][r], 0.125f, (float)gb4[r]);
                if (j0 + jj > igB) sc = -1e9f;
                const float pe = __expf(sc - 4.0f);
                rsB += pe;
                pt[r] = __float2bfloat16(pe);
            }
            *(uint2*)&Ps[prow + ct * 16 + lq * 4] = *(const uint2*)pt;
        }
        const v8s paB0 = *(const v8s*)&Ps[prow + lq * 8];
        const v8s paB1 = *(const v8s*)&Ps[prow + 32 + lq * 8];
        // PV both sets; v-frags read once, feed 4 MFMAs each
#pragma unroll
        for (int dt = 0; dt < 4; ++dt) {
            const v8s vb0 = *(const v8s*)&Vs[(dt * 16 + lm) * 72 + lq * 8];
            const v8s vb1 = *(const v8s*)&Vs[(dt * 16 + lm) * 72 + 32 + lq * 8];
            accA[dt] = MFMA(paA0, vb0, accA[dt]);
            accA[dt] = MFMA(paA1, vb1, accA[dt]);
            accB[dt] = MFMA(paB0, vb0, accB[dt]);
            accB[dt] = MFMA(paB1, vb1, accB[dt]);
        }
    }
    // denominators: sum the 4 lq replicas of each q-row, broadcast to acc rows
    rsA += __shfl_xor(rsA, 16, 64);
    rsA += __shfl_xor(rsA, 32, 64);
    rsB += __shfl_xor(rsB, 16, 64);
    rsB += __shfl_xor(rsB, 32, 64);
    float denA[4], denB[4];
#pragma unroll
    for (int r = 0; r < 4; ++r) {
        denA[r] = __shfl(rsA, lq * 4 + r, 64);
        denB[r] = __shfl(rsB, lq * 4 + r, 64);
    }
#pragma unroll
    for (int dt = 0; dt < 4; ++dt) {
#pragma unroll
        for (int r = 0; r < 4; ++r) {
            const int rowA = i0 + w * 32 + lq * 4 + r;
            const int d    = dt * 16 + lm;
            AO[((size_t)b * 2048 + rowA) * 1024 + h * 64 + d] =
                __float2bfloat16(accA[dt][r] / denA[r]);
            AO[((size_t)b * 2048 + rowA + 16) * 1024 + h * 64 + d] =
                __float2bfloat16(accB[dt][r] / denB[r]);
        }
    }
}

// ---------------------------------------------------------------------------
extern "C" void kernel_launch(void* const* d_in, const int* in_sizes, int n_in,
                              void* d_out, int out_size, void* d_ws, size_t ws_size,
                              hipStream_t stream)
{
    const float* x  = (const float*)d_in[0];
    const float* Wq = (const float*)d_in[1];
    const float* bq = (const float*)d_in[2];
    const float* Wk = (const float*)d_in[3];
    const float* bk = (const float*)d_in[4];
    const float* Wv = (const float*)d_in[5];
    const float* bv = (const float*)d_in[6];
    const float* Er = (const float*)d_in[7];
    const float* Wo = (const float*)d_in[8];
    const float* bo = (const float*)d_in[9];
    float* out = (float*)d_out;

    bf16* ws = (bf16*)d_ws;
    const size_t NEl = (size_t)4096 * 1024;
    bf16* Qw  = ws;                 // (b,h,s,d); K follows contiguously
    bf16* Kw  = ws + NEl;
    bf16* Vtw = ws + 3 * NEl;       // (b,h,d,s) — written directly by gemm z==2
    bf16* xb  = ws + 4 * NEl;       // bf16 x; dead after QKV gemm
    bf16* AOw = xb;                 // aliased
    bf16* Wqb = ws + 5 * NEl;       // Wq|Wk|Wv contiguous -> one N=3072 GEMM
    bf16* Wkb = Wqb + 1024 * 1024;
    bf16* Wvb = Wkb + 1024 * 1024;
    bf16* Wob = Wvb + 1024 * 1024;
    bf16* Erb = Wob + 1024 * 1024;
    (void)Kw;

    cast_all<<<dim3(4096, 6), 256, 0, stream>>>(x, Wq, Wk, Wv, Wo, Er,
                                                xb, Wqb, Wkb, Wvb, Wob, Erb);
    // fused QKV: N=3072 over contiguous Wq|Wk|Wv; Q,K headmajor; V -> Vt direct
    gemm_nt<<<dim3(24, 32), 256, 0, stream>>>(xb, Wqb, bq, bk, bv, Qw, Vtw, nullptr);
    attn<<<dim3(512), 256, 0, stream>>>(Qw, Kw, Vtw, Erb, AOw);
    // output projection: N=1024, fp32 rowmajor into d_out
    gemm_nt<<<dim3(8, 32), 256, 0, stream>>>(AOw, Wob, bo, bo, bo, nullptr, nullptr, out);
}